// Round 12
// baseline (119.592 us; speedup 1.0000x reference)
//
#include <hip/hip_runtime.h>

#define N_REAL 12
#define BATCH  4
#define CH     3
#define HH     256
#define WW     256
#define KK     4
#define TY     8                  // output rows per block (4 waves x 2 rows)
#define NTHR   256
#define HW     (HH * WW)
#define WROWS  5                  // input rows each wave consumes

typedef float f32x4 __attribute__((ext_vector_type(4)));
typedef float f32x2 __attribute__((ext_vector_type(2)));

__device__ __forceinline__ float sigmoidf(float x) {
    float e = __builtin_amdgcn_exp2f(x * -1.44269504088896340736f);
    return __builtin_amdgcn_rcpf(1.0f + e);
}

__global__ __launch_bounds__(NTHR, 4)   // cap 128 VGPR; must not spill
void reverb_fused(const float* __restrict__ states,
                  const float* __restrict__ weights,
                  const float* __restrict__ bias,
                  float*       __restrict__ out)
{
    const int ty  = blockIdx.x;            // 0..31
    const int b   = blockIdx.y;            // batch
    const int v   = blockIdx.z;            // dest node
    const int tid = threadIdx.x;
    const int w   = tid >> 6;              // wave: owns output rows gy0+2w, 2w+1
    const int ln  = tid & 63;              // lane: owns cols 4ln..4ln+3
    const int gy0 = ty * TY;
    const int deg = (v == 0) ? 4 : 3;

    const bool lE = (ln == 0);
    const bool rE = (ln == 63);
    const int aOff = lE ? 0 : -1;          // x-1 load (masked at left edge)
    const int cOff = rE ? 0 : 4;           // x+4 load (masked at right edge)

    // ---- per-row gather offsets (dwords), y clamped; rowok wave-uniform ----
    int  goffs[WROWS];
    bool rowok[WROWS];
    #pragma unroll
    for (int k = 0; k < WROWS; ++k) {
        const int gy  = gy0 + 2 * w - 1 + k;
        const int gyc = gy < 0 ? 0 : (gy > HH - 1 ? HH - 1 : gy);
        goffs[k] = gyc * WW + 4 * ln;
        rowok[k] = (unsigned)gy < (unsigned)HH;
    }

    // ---- edge tables (uniform) ----
    int ucA[4], eA[4];
    #pragma unroll
    for (int ei = 0; ei < 4; ++ei) {
        int t = v + 11 - ei; if (t >= 12) t -= 12;
        ucA[ei] = (ei == 3) ? 12 : t;
        eA[ei]  = (ei == 3) ? 36 : (ucA[ei] * 3 + ei);
    }

    float bsum[CH] = {0.f, 0.f, 0.f};
    for (int ei = 0; ei < deg; ++ei) {
        bsum[0] += bias[eA[ei] * CH + 0];
        bsum[1] += bias[eA[ei] * CH + 1];
        bsum[2] += bias[eA[ei] * CH + 2];
    }

    float acc[CH][2][4];
    #pragma unroll
    for (int co = 0; co < CH; ++co)
        #pragma unroll
        for (int yy = 0; yy < 2; ++yy)
            #pragma unroll
            for (int p = 0; p < 4; ++p) acc[co][yy][p] = 0.0f;

    for (int ei = 0; ei < deg; ++ei) {
        const float* __restrict__ srcE  =
            states + (size_t)(ucA[ei] * BATCH + b) * CH * HW;
        const float* __restrict__ wbase = weights + eA[ei] * (CH * CH * KK * KK);

        #pragma unroll
        for (int ci = 0; ci < CH; ++ci) {
            const float* __restrict__ srcC = srcC = srcE + (size_t)ci * HW;

            // ---- issue all 15 loads for this phase (A/C hit B's L1 lines) ----
            float a[WROWS]; f32x4 bq[WROWS]; f32x2 cq[WROWS];
            #pragma unroll
            for (int k = 0; k < WROWS; ++k) {
                const float* rp = srcC + goffs[k];
                a[k]  = rp[aOff];
                bq[k] = *(const f32x4*)rp;
                cq[k] = *(const f32x2*)(rp + cOff);
            }

            // ---- per row: sigmoid (masked) -> FMA ----
            #pragma unroll
            for (int lr = 0; lr < WROWS; ++lr) {
                float vv[7];
                if (rowok[lr]) {
                    vv[0] = lE ? 0.f : sigmoidf(a[lr]);
                    vv[1] = sigmoidf(bq[lr].x);
                    vv[2] = sigmoidf(bq[lr].y);
                    vv[3] = sigmoidf(bq[lr].z);
                    vv[4] = sigmoidf(bq[lr].w);
                    vv[5] = rE ? 0.f : sigmoidf(cq[lr].x);
                    vv[6] = rE ? 0.f : sigmoidf(cq[lr].y);
                } else {
                    #pragma unroll
                    for (int j = 0; j < 7; ++j) vv[j] = 0.f;
                }
                #pragma unroll
                for (int yy = 0; yy < 2; ++yy) {
                    const int ky = lr - yy;
                    if (ky < 0 || ky > 3) continue;
                    #pragma unroll
                    for (int co = 0; co < CH; ++co) {
                        const f32x4 wv =
                            *(const f32x4*)(wbase + ((co * CH + ci) * KK + ky) * KK);
                        #pragma unroll
                        for (int p = 0; p < 4; ++p) {
                            acc[co][yy][p] = fmaf(wv.x, vv[p + 0], acc[co][yy][p]);
                            acc[co][yy][p] = fmaf(wv.y, vv[p + 1], acc[co][yy][p]);
                            acc[co][yy][p] = fmaf(wv.z, vv[p + 2], acc[co][yy][p]);
                            acc[co][yy][p] = fmaf(wv.w, vv[p + 3], acc[co][yy][p]);
                        }
                    }
                }
            }
        }
    }

    const float inv = 1.0f / (float)deg;
    const size_t obase = (size_t)(v * BATCH + b) * CH * HW;
    #pragma unroll
    for (int co = 0; co < CH; ++co) {
        #pragma unroll
        for (int yy = 0; yy < 2; ++yy) {
            const int oy = gy0 + 2 * w + yy;
            f32x4 o;
            o.x = (acc[co][yy][0] + bsum[co]) * inv;
            o.y = (acc[co][yy][1] + bsum[co]) * inv;
            o.z = (acc[co][yy][2] + bsum[co]) * inv;
            o.w = (acc[co][yy][3] + bsum[co]) * inv;
            __builtin_nontemporal_store(o,
                (f32x4*)&out[obase + (size_t)co * HW + (size_t)oy * WW + 4 * ln]);
        }
    }
}

extern "C" void kernel_launch(void* const* d_in, const int* in_sizes, int n_in,
                              void* d_out, int out_size, void* d_ws, size_t ws_size,
                              hipStream_t stream)
{
    const float* states  = (const float*)d_in[0];
    const float* weights = (const float*)d_in[1];
    const float* bias    = (const float*)d_in[2];
    float*       out     = (float*)d_out;

    dim3 grid(HH / TY, BATCH, N_REAL);     // 32 x 4 x 12 = 1536 blocks
    reverb_fused<<<grid, NTHR, 0, stream>>>(states, weights, bias, out);
}

// Round 13
// 119.405 us; speedup vs baseline: 1.0016x; 1.0016x over previous
//
#include <hip/hip_runtime.h>

#define N_REAL 12
#define BATCH  4
#define CH     3
#define HH     256
#define WW     256
#define KK     4
#define TY     8                  // output rows per block (4 waves x 2 rows)
#define NTHR   256
#define HW     (HH * WW)
#define WROWS  5                  // input rows each wave consumes

typedef float f32x4 __attribute__((ext_vector_type(4)));
typedef float f32x2 __attribute__((ext_vector_type(2)));

__device__ __forceinline__ float sigmoidf(float x) {
    float e = __builtin_amdgcn_exp2f(x * -1.44269504088896340736f);
    return __builtin_amdgcn_rcpf(1.0f + e);
}

__global__ __launch_bounds__(NTHR)
__attribute__((amdgpu_waves_per_eu(4, 4)))   // pin: budget 128 VGPR, DON'T spill for 8/EU
void reverb_fused(const float* __restrict__ states,
                  const float* __restrict__ weights,
                  const float* __restrict__ bias,
                  float*       __restrict__ out)
{
    const int ty  = blockIdx.x;            // 0..31
    const int b   = blockIdx.y;            // batch
    const int v   = blockIdx.z;            // dest node
    const int tid = threadIdx.x;
    const int w   = tid >> 6;              // wave: owns output rows gy0+2w, 2w+1
    const int ln  = tid & 63;              // lane: owns cols 4ln..4ln+3
    const int gy0 = ty * TY;
    const int deg = (v == 0) ? 4 : 3;

    const bool lE = (ln == 0);
    const bool rE = (ln == 63);
    const int aOff = lE ? 0 : -1;          // x-1 load (address-clamped at left edge)
    const int cOff = rE ? 0 : 4;           // x+4 load (address-clamped at right edge)

    // ---- per-row gather offsets (dwords), y clamped; rowok wave-uniform ----
    int  goffs[WROWS];
    bool rowok[WROWS];
    #pragma unroll
    for (int k = 0; k < WROWS; ++k) {
        const int gy  = gy0 + 2 * w - 1 + k;
        const int gyc = gy < 0 ? 0 : (gy > HH - 1 ? HH - 1 : gy);
        goffs[k] = gyc * WW + 4 * ln;
        rowok[k] = (unsigned)gy < (unsigned)HH;
    }

    // ---- edge tables (uniform) ----
    int ucA[4], eA[4];
    #pragma unroll
    for (int ei = 0; ei < 4; ++ei) {
        int t = v + 11 - ei; if (t >= 12) t -= 12;
        ucA[ei] = (ei == 3) ? 12 : t;
        eA[ei]  = (ei == 3) ? 36 : (ucA[ei] * 3 + ei);
    }

    float bsum[CH] = {0.f, 0.f, 0.f};
    for (int ei = 0; ei < deg; ++ei) {
        bsum[0] += bias[eA[ei] * CH + 0];
        bsum[1] += bias[eA[ei] * CH + 1];
        bsum[2] += bias[eA[ei] * CH + 2];
    }

    float acc[CH][2][4];
    #pragma unroll
    for (int co = 0; co < CH; ++co)
        #pragma unroll
        for (int yy = 0; yy < 2; ++yy)
            #pragma unroll
            for (int p = 0; p < 4; ++p) acc[co][yy][p] = 0.0f;

    for (int ei = 0; ei < deg; ++ei) {
        const float* __restrict__ srcE  =
            states + (size_t)(ucA[ei] * BATCH + b) * CH * HW;
        const float* __restrict__ wbase = weights + eA[ei] * (CH * CH * KK * KK);

        #pragma unroll
        for (int ci = 0; ci < CH; ++ci) {
            const float* __restrict__ srcC = srcE + (size_t)ci * HW;

            // ---- issue all 15 loads for this phase (A/C hit B's cache lines) ----
            float a[WROWS]; f32x4 bq[WROWS]; f32x2 cq[WROWS];
            #pragma unroll
            for (int k = 0; k < WROWS; ++k) {
                const float* rp = srcC + goffs[k];
                a[k]  = rp[aOff];
                bq[k] = *(const f32x4*)rp;
                cq[k] = *(const f32x2*)(rp + cOff);
            }

            // ---- per row: sigmoid (masked) -> FMA ----
            #pragma unroll
            for (int lr = 0; lr < WROWS; ++lr) {
                float vv[7];
                if (rowok[lr]) {
                    vv[0] = lE ? 0.f : sigmoidf(a[lr]);
                    vv[1] = sigmoidf(bq[lr].x);
                    vv[2] = sigmoidf(bq[lr].y);
                    vv[3] = sigmoidf(bq[lr].z);
                    vv[4] = sigmoidf(bq[lr].w);
                    vv[5] = rE ? 0.f : sigmoidf(cq[lr].x);
                    vv[6] = rE ? 0.f : sigmoidf(cq[lr].y);
                } else {
                    #pragma unroll
                    for (int j = 0; j < 7; ++j) vv[j] = 0.f;
                }
                #pragma unroll
                for (int yy = 0; yy < 2; ++yy) {
                    const int ky = lr - yy;
                    if (ky < 0 || ky > 3) continue;
                    #pragma unroll
                    for (int co = 0; co < CH; ++co) {
                        const f32x4 wv =
                            *(const f32x4*)(wbase + ((co * CH + ci) * KK + ky) * KK);
                        #pragma unroll
                        for (int p = 0; p < 4; ++p) {
                            acc[co][yy][p] = fmaf(wv.x, vv[p + 0], acc[co][yy][p]);
                            acc[co][yy][p] = fmaf(wv.y, vv[p + 1], acc[co][yy][p]);
                            acc[co][yy][p] = fmaf(wv.z, vv[p + 2], acc[co][yy][p]);
                            acc[co][yy][p] = fmaf(wv.w, vv[p + 3], acc[co][yy][p]);
                        }
                    }
                }
            }
        }
    }

    const float inv = 1.0f / (float)deg;
    const size_t obase = (size_t)(v * BATCH + b) * CH * HW;
    #pragma unroll
    for (int co = 0; co < CH; ++co) {
        #pragma unroll
        for (int yy = 0; yy < 2; ++yy) {
            const int oy = gy0 + 2 * w + yy;
            f32x4 o;
            o.x = (acc[co][yy][0] + bsum[co]) * inv;
            o.y = (acc[co][yy][1] + bsum[co]) * inv;
            o.z = (acc[co][yy][2] + bsum[co]) * inv;
            o.w = (acc[co][yy][3] + bsum[co]) * inv;
            __builtin_nontemporal_store(o,
                (f32x4*)&out[obase + (size_t)co * HW + (size_t)oy * WW + 4 * ln]);
        }
    }
}

extern "C" void kernel_launch(void* const* d_in, const int* in_sizes, int n_in,
                              void* d_out, int out_size, void* d_ws, size_t ws_size,
                              hipStream_t stream)
{
    const float* states  = (const float*)d_in[0];
    const float* weights = (const float*)d_in[1];
    const float* bias    = (const float*)d_in[2];
    float*       out     = (float*)d_out;

    dim3 grid(HH / TY, BATCH, N_REAL);     // 32 x 4 x 12 = 1536 blocks
    reverb_fused<<<grid, NTHR, 0, stream>>>(states, weights, bias, out);
}

// Round 14
// 52.565 us; speedup vs baseline: 2.2751x; 2.2716x over previous
//
#include <hip/hip_runtime.h>

#define N_REAL 12
#define BATCH  4
#define CH     3
#define HH     256
#define WW     256
#define KK     4
#define TY     8                  // output rows per block (4 waves x 2 rows)
#define ROWSR  11                 // TY + KK - 1 input rows per channel
#define RSTR   264                // LDS row stride (dwords): 256 data + 8 zero pad
#define PL     (ROWSR * RSTR)     // plane = 2904 dwords
#define NTHR   256
#define HW     (HH * WW)
#define NROWS3 (CH * ROWSR)       // 33 rows to stage per edge

typedef float f32x4 __attribute__((ext_vector_type(4)));

__device__ __forceinline__ float sigmoidf(float x) {
    float e = __builtin_amdgcn_exp2f(x * -1.44269504088896340736f);
    return __builtin_amdgcn_rcpf(1.0f + e);
}

__global__ __launch_bounds__(NTHR, 4)
void reverb_fused(const float* __restrict__ states,
                  const float* __restrict__ weights,
                  const float* __restrict__ bias,
                  float*       __restrict__ out)
{
    // guard(4) + 3 planes of 11 rows x 264; every pad stays zero -> free x-halo.
    __shared__ __align__(16) float S[4 + CH * PL];   // 34.9 KB -> 4 blocks/CU

    const int ty  = blockIdx.x;            // 0..31
    const int b   = blockIdx.y;            // batch
    const int v   = blockIdx.z;            // dest node
    const int tid = threadIdx.x;
    const int w   = tid >> 6;              // wave: owns output rows gy0+2w, 2w+1
    const int ln  = tid & 63;              // lane: owns cols 4ln..4ln+3
    const int gy0 = ty * TY;
    const int deg = (v == 0) ? 4 : 3;

    // ---- one-time zero of guard + all row pads (4 + 33*8 = 268 dwords) ----
    #pragma unroll
    for (int z = 0; z < 2; ++z) {
        const int i = tid + z * NTHR;
        if (i < 4) S[i] = 0.0f;
        else if (i < 4 + NROWS3 * 8) {
            const int j = i - 4;
            S[4 + (j >> 3) * RSTR + 256 + (j & 7)] = 0.0f;
        }
    }

    // ---- edge tables (uniform) ----
    int ucA[4], eA[4];
    #pragma unroll
    for (int ei = 0; ei < 4; ++ei) {
        int t = v + 11 - ei; if (t >= 12) t -= 12;
        ucA[ei] = (ei == 3) ? 12 : t;
        eA[ei]  = (ei == 3) ? 36 : (ucA[ei] * 3 + ei);
    }

    float bsum[CH] = {0.f, 0.f, 0.f};
    for (int ei = 0; ei < deg; ++ei) {
        bsum[0] += bias[eA[ei] * CH + 0];
        bsum[1] += bias[eA[ei] * CH + 1];
        bsum[2] += bias[eA[ei] * CH + 2];
    }

    float acc[CH][2][4];
    #pragma unroll
    for (int co = 0; co < CH; ++co)
        #pragma unroll
        for (int yy = 0; yy < 2; ++yy)
            #pragma unroll
            for (int p = 0; p < 4; ++p) acc[co][yy][p] = 0.0f;

    for (int ei = 0; ei < deg; ++ei) {
        const float* __restrict__ srcE  =
            states + (size_t)(ucA[ei] * BATCH + b) * CH * HW;
        const float* __restrict__ wbase = weights + eA[ei] * (CH * CH * KK * KK);

        __syncthreads();                   // previous edge's readers done

        // ---- stage 33 rows (3 channels), wave w handles idx = w+4j ----
        #pragma unroll
        for (int j = 0; j < 9; ++j) {
            const int idx = w + 4 * j;
            if (idx < NROWS3) {            // wave-uniform
                const int ci = idx / ROWSR;
                const int r  = idx - ci * ROWSR;
                const int gy = gy0 + r - 1;               // SAME pad lo=1
                const int gyc = gy < 0 ? 0 : (gy > HH - 1 ? HH - 1 : gy);
                const f32x4 q = *(const f32x4*)(srcE + (size_t)ci * HW + gyc * WW + 4 * ln);
                f32x4 t;
                if ((unsigned)gy < (unsigned)HH) {
                    t.x = sigmoidf(q.x); t.y = sigmoidf(q.y);
                    t.z = sigmoidf(q.z); t.w = sigmoidf(q.w);
                } else {
                    t = (f32x4){0.f, 0.f, 0.f, 0.f};
                }
                *(f32x4*)(S + 4 + ci * PL + r * RSTR + 4 * ln) = t;
            }
        }
        __syncthreads();                   // edge tile ready

        // ---- compute: 3 channels x 5 rows -> 1152 FMA per thread ----
        #pragma unroll
        for (int ci = 0; ci < CH; ++ci) {
            #pragma unroll
            for (int lr = 0; lr < 5; ++lr) {
                const float* rp = S + 4 + ci * PL + (2 * w + lr) * RSTR + 4 * ln;
                const f32x4 A  = *(const f32x4*)(rp - 4);   // A.w = x-1 (pad/guard)
                const f32x4 Bq = *(const f32x4*)(rp);
                const f32x4 Cq = *(const f32x4*)(rp + 4);   // C.x,C.y = x+4,x+5
                const float vv[7] = {A.w, Bq.x, Bq.y, Bq.z, Bq.w, Cq.x, Cq.y};
                #pragma unroll
                for (int yy = 0; yy < 2; ++yy) {
                    const int ky = lr - yy;
                    if (ky < 0 || ky > 3) continue;
                    #pragma unroll
                    for (int co = 0; co < CH; ++co) {
                        const f32x4 wv =
                            *(const f32x4*)(wbase + ((co * CH + ci) * KK + ky) * KK);
                        #pragma unroll
                        for (int p = 0; p < 4; ++p) {
                            acc[co][yy][p] = fmaf(wv.x, vv[p + 0], acc[co][yy][p]);
                            acc[co][yy][p] = fmaf(wv.y, vv[p + 1], acc[co][yy][p]);
                            acc[co][yy][p] = fmaf(wv.z, vv[p + 2], acc[co][yy][p]);
                            acc[co][yy][p] = fmaf(wv.w, vv[p + 3], acc[co][yy][p]);
                        }
                    }
                }
            }
        }
    }

    const float inv = 1.0f / (float)deg;
    const size_t obase = (size_t)(v * BATCH + b) * CH * HW;
    #pragma unroll
    for (int co = 0; co < CH; ++co) {
        #pragma unroll
        for (int yy = 0; yy < 2; ++yy) {
            const int oy = gy0 + 2 * w + yy;
            f32x4 o;
            o.x = (acc[co][yy][0] + bsum[co]) * inv;
            o.y = (acc[co][yy][1] + bsum[co]) * inv;
            o.z = (acc[co][yy][2] + bsum[co]) * inv;
            o.w = (acc[co][yy][3] + bsum[co]) * inv;
            __builtin_nontemporal_store(o,
                (f32x4*)&out[obase + (size_t)co * HW + (size_t)oy * WW + 4 * ln]);
        }
    }
}

extern "C" void kernel_launch(void* const* d_in, const int* in_sizes, int n_in,
                              void* d_out, int out_size, void* d_ws, size_t ws_size,
                              hipStream_t stream)
{
    const float* states  = (const float*)d_in[0];
    const float* weights = (const float*)d_in[1];
    const float* bias    = (const float*)d_in[2];
    float*       out     = (float*)d_out;

    dim3 grid(HH / TY, BATCH, N_REAL);     // 32 x 4 x 12 = 1536 blocks
    reverb_fused<<<grid, NTHR, 0, stream>>>(states, weights, bias, out);
}